// Round 19
// baseline (83.171 us; speedup 1.0000x reference)
//
#include <hip/hip_runtime.h>
#include <hip/hip_fp16.h>

#define HH 256
#define WW 704
#define DD 64
#define CC 3
#define BB 2
#define HWN (HH * WW)       // 180224

#define TY 16               // out-tile rows
#define TX 16               // out-tile cols
#define RY0 20              // q0 region rows (tile + 2*2 halo)
#define RX0 20              // q0 region cols
#define NP0 (RY0 * RX0)     // 400
#define RY1 18              // q1 region rows (tile + 2*1 halo)
#define RX1 18              // q1 region cols
#define NP1 (RY1 * RX1)     // 324
#define NTX (WW / TX)       // 44
#define NTY (HH / TY)       // 16
#define NTILES (NTX * NTY)  // 704 (divisible by 8 -> bijective XCD swizzle)

static constexpr float INV2Z2 = 1.0f / (2.0f * 1e-3f * 1e-3f);
static constexpr float LOG2E  = 1.4426950408889634f;

__device__ __forceinline__ float fexp2(float x) {
#if __has_builtin(__builtin_amdgcn_exp2f)
    return __builtin_amdgcn_exp2f(x);
#else
    return __expf(x * 0.6931471805599453f);
#endif
}

// ---------------------------------------------------------------------------
// Affinity: kaffp[(b*HWN+n)*12 + tap] = LOG2E * ws * exp(-ssd/(2 zeta^2)).
// Px-major stride-12 records: fused kernel reads 9 taps as 3 x float4.
// ---------------------------------------------------------------------------
__global__ __launch_bounds__(256) void affinity_kernel(
    const float* __restrict__ color, const float* __restrict__ wsp,
    float* __restrict__ kaffp)
{
    int n = blockIdx.x * 256 + threadIdx.x;
    int b = blockIdx.y;
    int h = n / WW, w = n - h * WW;
    float wsv = wsp[0] * LOG2E;

    const float* cb = color + (size_t)b * CC * HWN + n;
    float c0 = cb[0], c1 = cb[HWN], c2 = cb[2 * HWN];
    bool hm = h > 0, hp = h < HH - 1, wm = w > 0, wp = w < WW - 1;

    float kk[9];
#pragma unroll
    for (int dh = -1; dh <= 1; ++dh) {
#pragma unroll
        for (int dw = -1; dw <= 1; ++dw) {
            int k = (dh + 1) * 3 + (dw + 1);
            bool valid = (dh < 0 ? hm : (dh > 0 ? hp : true)) &&
                         (dw < 0 ? wm : (dw > 0 ? wp : true));
            int off = valid ? (dh * WW + dw) : 0;
            float u0 = valid ? cb[off] : 0.f;
            float u1 = valid ? cb[HWN + off] : 0.f;
            float u2 = valid ? cb[2 * HWN + off] : 0.f;
            float d0 = u0 - c0, d1 = u1 - c1, d2 = u2 - c2;
            float ss = d0 * d0 + d1 * d1 + d2 * d2;
            kk[k] = wsv * __expf(-ss * INV2Z2);
        }
    }
    float* kp = kaffp + ((size_t)b * HWN + n) * 12;
    *(float4*)(kp + 0) = make_float4(kk[0], kk[1], kk[2], kk[3]);
    *(float4*)(kp + 4) = make_float4(kk[4], kk[5], kk[6], kk[7]);
    *(float4*)(kp + 8) = make_float4(kk[8], 0.f, 0.f, 0.f);
}

// ---------------------------------------------------------------------------
// LDS layout: px-major, 32 dwords (64 f16 ch) per px, XOR swizzle on dword
// index: dw(p,q) = p*32 + (q ^ ((p&7)<<2)). Same permutation on store/load.
// ---------------------------------------------------------------------------
__device__ __forceinline__ void acc_tap(const unsigned* q, int p0, int cg,
                                        __half2 kh, __half2* tv2) {
    int ia = p0 * 32 + ((cg * 8) ^ ((p0 & 7) << 2));
    int ib = ia ^ 4;
    const __half2* qa = (const __half2*)&q[ia];
    const __half2* qb = (const __half2*)&q[ib];
    tv2[0] = __hfma2(kh, qa[0], tv2[0]);
    tv2[1] = __hfma2(kh, qa[1], tv2[1]);
    tv2[2] = __hfma2(kh, qa[2], tv2[2]);
    tv2[3] = __hfma2(kh, qa[3], tv2[3]);
    tv2[4] = __hfma2(kh, qb[0], tv2[4]);
    tv2[5] = __hfma2(kh, qb[1], tv2[5]);
    tv2[6] = __hfma2(kh, qb[2], tv2[6]);
    tv2[7] = __hfma2(kh, qb[3], tv2[7]);
}

__device__ __forceinline__ void ld_raw(const unsigned* q, int p, int cg,
                                       uint4& a, uint4& bu) {
    int ia = p * 32 + ((cg * 8) ^ ((p & 7) << 2));
    a  = *(const uint4*)&q[ia];
    bu = *(const uint4*)&q[ia ^ 4];
}

__device__ __forceinline__ void unpack_px(uint4 a, uint4 bu, float* qc) {
    const __half2* pa = (const __half2*)&a;
    const __half2* pb = (const __half2*)&bu;
#pragma unroll
    for (int j = 0; j < 4; ++j) {
        float2 f = __half22float2(pa[j]);
        qc[2 * j] = f.x; qc[2 * j + 1] = f.y;
    }
#pragma unroll
    for (int j = 0; j < 4; ++j) {
        float2 f = __half22float2(pb[j]);
        qc[8 + 2 * j] = f.x; qc[8 + 2 * j + 1] = f.y;
    }
}

__device__ __forceinline__ void pack_px(const float* u, float scale,
                                        uint4& a, uint4& bu) {
    __half2* pa = (__half2*)&a;
    __half2* pb = (__half2*)&bu;
    pa[0] = __floats2half2_rn(u[0]  * scale, u[1]  * scale);
    pa[1] = __floats2half2_rn(u[2]  * scale, u[3]  * scale);
    pa[2] = __floats2half2_rn(u[4]  * scale, u[5]  * scale);
    pa[3] = __floats2half2_rn(u[6]  * scale, u[7]  * scale);
    pb[0] = __floats2half2_rn(u[8]  * scale, u[9]  * scale);
    pb[1] = __floats2half2_rn(u[10] * scale, u[11] * scale);
    pb[2] = __floats2half2_rn(u[12] * scale, u[13] * scale);
    pb[3] = __floats2half2_rn(u[14] * scale, u[15] * scale);
}

__device__ __forceinline__ void st_raw(unsigned* q, int p, int cg,
                                       uint4 a, uint4 bu) {
    int ia = p * 32 + ((cg * 8) ^ ((p & 7) << 2));
    *(uint4*)&q[ia] = a;
    *(uint4*)&q[ia ^ 4] = bu;
}

__device__ __forceinline__ void st_px(unsigned* q, int p, int cg,
                                      const float* u, float scale) {
    uint4 a, bu;
    pack_px(u, scale, a, bu);
    st_raw(q, p, cg, a, bu);
}

// 4-way exclusive prefix + totals over channel-groups
__device__ __forceinline__ void scan4(float Aloc, float Bloc, int pxl, int cg,
                                      float& Ar, float& Br, float& T, float& E) {
    float A0 = __shfl(Aloc, pxl),      A1 = __shfl(Aloc, pxl + 16),
          A2 = __shfl(Aloc, pxl + 32), A3 = __shfl(Aloc, pxl + 48);
    float B0 = __shfl(Bloc, pxl),      B1 = __shfl(Bloc, pxl + 16),
          B2 = __shfl(Bloc, pxl + 32), B3 = __shfl(Bloc, pxl + 48);
    T = A0 + A1 + A2 + A3;  E = B0 + B1 + B2 + B3;
    Ar = 0.f; Br = 0.f;
    if (cg > 0) { Ar += A0; Br += B0; }
    if (cg > 1) { Ar += A1; Br += B1; }
    if (cg > 2) { Ar += A2; Br += B2; }
}

// tv[i] = t[e] (log2e pre-scaled); qc = q0 center (softmax of ORIGINAL
// logits). q_new[d] = qc[d]*2^(-qhat2[d])/sum == softmax(lg - q_hat).
__device__ __forceinline__ float finish_mult(float* tv, const float* qc,
                                             int pxl, int cg) {
    float Aloc = 0.f, Bloc = 0.f;
#pragma unroll
    for (int i = 0; i < 16; ++i) {
        float e = (float)(cg * 16 + i);
        Aloc += tv[i]; Bloc += e * tv[i];
    }
    float Ar, Br, T, E;
    scan4(Aloc, Bloc, pxl, cg, Ar, Br, T, E);
    float s = 0.f;
#pragma unroll
    for (int i = 0; i < 16; ++i) {
        float e = (float)(cg * 16 + i);
        Ar += tv[i]; Br += e * tv[i];
        float qh2 = 2.f * (e * Ar - Br) + E - e * T;   // = q_hat * log2e
        tv[i] = qc[i] * fexp2(-qh2);
        s += tv[i];
    }
    s += __shfl_xor(s, 16);
    s += __shfl_xor(s, 32);
    return 1.f / s;
}

__device__ __forceinline__ void load_k(const float* kfbp, int n, int gy, int gx,
                                       float* k) {
    const float* kp = kfbp + (size_t)n * 12;
    float4 a = *(const float4*)(kp + 0);
    float4 bq = *(const float4*)(kp + 4);
    float4 c = *(const float4*)(kp + 8);
    k[0] = a.x; k[1] = a.y; k[2] = a.z; k[3] = a.w;
    k[4] = bq.x; k[5] = bq.y; k[6] = bq.z; k[7] = bq.w;
    k[8] = c.x;
    if (gy <= 0)      { k[0] = k[1] = k[2] = 0.f; }
    if (gy >= HH - 1) { k[6] = k[7] = k[8] = 0.f; }
    if (gx <= 0)      { k[0] = k[3] = k[6] = 0.f; }
    if (gx >= WW - 1) { k[2] = k[5] = k[8] = 0.f; }
}

__device__ __forceinline__ void stencil9(const unsigned* qs, int rowstride,
                                         int py, int px, int cg,
                                         const float* k, float* tv) {
    __half2 tv2[8];
#pragma unroll
    for (int j = 0; j < 8; ++j) tv2[j] = __float2half2_rn(0.f);
    int base = (py + 1) * rowstride + (px + 1);
#pragma unroll
    for (int tap = 0; tap < 9; ++tap) {
        int dy = tap / 3 - 1, dx = tap - (tap / 3) * 3 - 1;
        acc_tap(qs, base + dy * rowstride + dx, cg, __float2half2_rn(k[tap]), tv2);
    }
#pragma unroll
    for (int j = 0; j < 8; ++j) {
        float2 f = __half22float2(tv2[j]);
        tv[2 * j] = f.x; tv[2 * j + 1] = f.y;
    }
}

// ---------------------------------------------------------------------------
// Fused CRF per 16x16 out-tile (task = 1 px, 4 lanes x 16 ch), 512 threads.
// ONE LDS buffer (51.2 KB) holds q0, then q1 written IN-PLACE:
//   q1 slot id overwrites q0 slot id; q1 task id' reads q0 window starting at
//   id' + 2*floor(id'/18) > id for all id < id', so with per-round
//   {compute -> barrier -> write}, later rounds never read overwritten slots.
//   P0: q0 = softmax(logits) on 20x20 (4 rounds)
//   stash: q0 centers of this thread's two P2 px -> regs (before any write)
//   P1: 3 rounds of {compute q1 (<=128 tasks) -> barrier -> write slot id}
//   P2: 2 rounds, qhat2 from q1 stencil, base = stashed q0 -> global
// 16x16 tile cuts task-slots/px 5.0 -> 4.5 and halves block count.
// ---------------------------------------------------------------------------
__global__ __launch_bounds__(512) void fused_crf_kernel(
    const float* __restrict__ logits, const float* __restrict__ kaffp,
    float* __restrict__ qout)
{
    __shared__ unsigned qs[NP0 * 32];   // 51,200 B (q0, overwritten by q1)

    const int t = threadIdx.x;
    const int lane = t & 63;
    const int wv = t >> 6;          // 0..7
    const int pxl = lane & 15;
    const int cg = lane >> 4;       // channels [16cg, 16cg+16)
    const int b = blockIdx.y;
    const int tid16 = wv * 16 + pxl;  // 0..127

    const int bid = blockIdx.x;     // XCD swizzle (704 % 8 == 0 -> bijective)
    const int pb = (bid & 7) * (NTILES / 8) + (bid >> 3);
    const int tyr = pb / NTX, txc = pb - tyr * NTX;
    const int y0 = tyr * TY, x0 = txc * TX;

    const float* lgb = logits + ((size_t)b * DD + cg * 16) * HWN;
    const float* kfbp = kaffp + (size_t)b * HWN * 12;

    // ---------------- P0: q0 = softmax(logits) on 20x20 ----------------
    for (int r = 0; r < 4; ++r) {
        int id = r * 128 + tid16;
        if (id < NP0) {
            int py = id / RX0, px = id - py * RX0;
            int gy = min(max(y0 - 2 + py, 0), HH - 1);
            int gx = min(max(x0 - 2 + px, 0), WW - 1);
            const float* lg = lgb + gy * WW + gx;
            float v[16];
            float s = 0.f;
#pragma unroll
            for (int i = 0; i < 16; ++i) {
                v[i] = __expf(lg[(size_t)i * HWN]);
                s += v[i];
            }
            s += __shfl_xor(s, 16);
            s += __shfl_xor(s, 32);
            st_px(qs, id, cg, v, 1.0f / s);
        }
    }
    __syncthreads();

    // stash q0 centers for this thread's two P2 pixels (slots 42..357 get
    // overwritten by q1 writes; must read before round-0's write barrier)
    uint4 s0a, s0b, s1a, s1b;
    {
        int py = tid16 >> 4, px = tid16 & 15;
        ld_raw(qs, (py + 2) * RX0 + (px + 2), cg, s0a, s0b);
        int id2 = 128 + tid16;
        int py2 = id2 >> 4, px2 = id2 & 15;
        ld_raw(qs, (py2 + 2) * RX0 + (px2 + 2), cg, s1a, s1b);
    }

    // ---------------- P1: q1 on 18x18, 3 rounds, in-place ----------------
#pragma unroll
    for (int r = 0; r < 3; ++r) {
        int id = r * 128 + tid16;
        bool valid = (r < 2) || (id < NP1);
        uint4 a, bu;
        if (valid) {
            int py = id / RX1, px = id - py * RX1;
            int gy = y0 - 1 + py, gx = x0 - 1 + px;   // may be out of image
            int cy = min(max(gy, 0), HH - 1), cx = min(max(gx, 0), WW - 1);
            int n = cy * WW + cx;
            float k[9];
            load_k(kfbp, n, gy, gx, k);
            float tv[16];
            stencil9(qs, RX0, py, px, cg, k, tv);
            uint4 ca, cb2;
            ld_raw(qs, (py + 1) * RX0 + (px + 1), cg, ca, cb2);
            float qc[16];
            unpack_px(ca, cb2, qc);
            float inv = finish_mult(tv, qc, pxl, cg);
            pack_px(tv, inv, a, bu);
        }
        __syncthreads();              // all round-r q0 reads complete
        if (valid) st_raw(qs, id, cg, a, bu);
        // no barrier needed before next round's compute: its q0 reads are
        // strictly above all slots written so far (see header proof)
    }
    __syncthreads();   // q1 fully written

    // ---------------- P2: q2 -> global, 16x16, 2 rounds ----------------
#pragma unroll
    for (int r = 0; r < 2; ++r) {
        int id = r * 128 + tid16;            // 0..255, all valid
        int py = id >> 4, px = id & 15;
        int gy = y0 + py, gx = x0 + px;      // always in image
        int n = gy * WW + gx;

        float k[9];
        load_k(kfbp, n, gy, gx, k);

        float tv[16];
        stencil9(qs, RX1, py, px, cg, k, tv);
        float qc[16];
        unpack_px(r == 0 ? s0a : s1a, r == 0 ? s0b : s1b, qc);
        float inv = finish_mult(tv, qc, pxl, cg);

        float* qo = qout + ((size_t)b * DD + cg * 16) * HWN + n;
#pragma unroll
        for (int i = 0; i < 16; ++i) qo[(size_t)i * HWN] = tv[i] * inv;
    }
}

// ---------------------------------------------------------------------------
extern "C" void kernel_launch(void* const* d_in, const int* in_sizes, int n_in,
                              void* d_out, int out_size, void* d_ws, size_t ws_size,
                              hipStream_t stream) {
    const float* color  = (const float*)d_in[0];
    // d_in[1] = feats: unused by the forward pass
    const float* logits = (const float*)d_in[2];
    const float* wsp    = (const float*)d_in[3];

    float* q_out = (float*)d_out;
    float* kaffp = (float*)d_ws;          // [B,HW,12] f32 px-major, 17.3 MB

    dim3 gridA(HWN / 256, BB);
    affinity_kernel<<<gridA, 256, 0, stream>>>(color, wsp, kaffp);

    dim3 gridF(NTILES, BB);               // 704 tiles x 2 batches
    fused_crf_kernel<<<gridF, 512, 0, stream>>>(logits, kaffp, q_out);
}

// Round 20
// 80.237 us; speedup vs baseline: 1.0366x; 1.0366x over previous
//
#include <hip/hip_runtime.h>
#include <hip/hip_fp16.h>

#define HH 256
#define WW 704
#define DD 64
#define CC 3
#define BB 2
#define HWN (HH * WW)       // 180224

#define TY 8                // out-tile rows
#define TX 16               // out-tile cols
#define RY0 12              // q0 region rows (tile + 2*2 halo)
#define RX0 20              // q0 region cols
#define NP0 (RY0 * RX0)     // 240
#define RY1 10              // q1 region rows (tile + 2*1 halo)
#define RX1 18              // q1 region cols
#define NP1 (RY1 * RX1)     // 180
#define NTX (WW / TX)       // 44
#define NTY (HH / TY)       // 32
#define NTILES (NTX * NTY)  // 1408 (divisible by 8 -> bijective XCD swizzle)

static constexpr float INV2Z2 = 1.0f / (2.0f * 1e-3f * 1e-3f);
static constexpr float LOG2E  = 1.4426950408889634f;

__device__ __forceinline__ float fexp2(float x) {
#if __has_builtin(__builtin_amdgcn_exp2f)
    return __builtin_amdgcn_exp2f(x);
#else
    return __expf(x * 0.6931471805599453f);
#endif
}

// ---------------------------------------------------------------------------
// Affinity: per px, 9 taps of LOG2E*ws*exp(-ssd/(2 zeta^2)), PRE-MASKED
// (0 for out-of-image taps; equivalent to the reference's zero-padded uq)
// and stored as DUPLICATED half2 (tap j -> dword j = (f16(k),f16(k))),
// px-major stride 12 dwords (48B, 16B-aligned). The fused kernel then feeds
// __hfma2 directly: no per-task masks, no f32->f16 converts.
// ---------------------------------------------------------------------------
__global__ __launch_bounds__(256) void affinity_kernel(
    const float* __restrict__ color, const float* __restrict__ wsp,
    unsigned* __restrict__ kaffp)
{
    int n = blockIdx.x * 256 + threadIdx.x;
    int b = blockIdx.y;
    int h = n / WW, w = n - h * WW;
    float wsv = wsp[0] * LOG2E;

    const float* cb = color + (size_t)b * CC * HWN + n;
    float c0 = cb[0], c1 = cb[HWN], c2 = cb[2 * HWN];
    bool hm = h > 0, hp = h < HH - 1, wm = w > 0, wp = w < WW - 1;

    unsigned kk[9];
#pragma unroll
    for (int dh = -1; dh <= 1; ++dh) {
#pragma unroll
        for (int dw = -1; dw <= 1; ++dw) {
            int k = (dh + 1) * 3 + (dw + 1);
            bool valid = (dh < 0 ? hm : (dh > 0 ? hp : true)) &&
                         (dw < 0 ? wm : (dw > 0 ? wp : true));
            int off = valid ? (dh * WW + dw) : 0;
            float u0 = cb[off], u1 = cb[HWN + off], u2 = cb[2 * HWN + off];
            float d0 = u0 - c0, d1 = u1 - c1, d2 = u2 - c2;
            float ss = d0 * d0 + d1 * d1 + d2 * d2;
            float kv = valid ? wsv * __expf(-ss * INV2Z2) : 0.f;
            __half2 h2 = __float2half2_rn(kv);
            kk[k] = *(unsigned*)&h2;
        }
    }
    unsigned* kp = kaffp + ((size_t)b * HWN + n) * 12;
    *(uint4*)(kp + 0) = make_uint4(kk[0], kk[1], kk[2], kk[3]);
    *(uint4*)(kp + 4) = make_uint4(kk[4], kk[5], kk[6], kk[7]);
    kp[8] = kk[8];
}

// ---------------------------------------------------------------------------
// LDS layout: px-major, 32 dwords (64 f16 ch) per px, XOR swizzle on dword
// index: dw(p,q) = p*32 + (q ^ ((p&7)<<2)). Same permutation on store and
// load -> correctness independent of the mixing.
// ---------------------------------------------------------------------------
__device__ __forceinline__ void acc_tap(const unsigned* q, int p0, int cg,
                                        __half2 kh, __half2* tv2) {
    int ia = p0 * 32 + ((cg * 8) ^ ((p0 & 7) << 2));
    int ib = ia ^ 4;
    const __half2* qa = (const __half2*)&q[ia];
    const __half2* qb = (const __half2*)&q[ib];
    tv2[0] = __hfma2(kh, qa[0], tv2[0]);
    tv2[1] = __hfma2(kh, qa[1], tv2[1]);
    tv2[2] = __hfma2(kh, qa[2], tv2[2]);
    tv2[3] = __hfma2(kh, qa[3], tv2[3]);
    tv2[4] = __hfma2(kh, qb[0], tv2[4]);
    tv2[5] = __hfma2(kh, qb[1], tv2[5]);
    tv2[6] = __hfma2(kh, qb[2], tv2[6]);
    tv2[7] = __hfma2(kh, qb[3], tv2[7]);
}

// read the two packed uint4 of px p (this cg)
__device__ __forceinline__ void ld_raw(const unsigned* q, int p, int cg,
                                       uint4& a, uint4& bu) {
    int ia = p * 32 + ((cg * 8) ^ ((p & 7) << 2));
    a  = *(const uint4*)&q[ia];
    bu = *(const uint4*)&q[ia ^ 4];
}

// unpack two packed uint4 -> 16 f32
__device__ __forceinline__ void unpack_px(uint4 a, uint4 bu, float* qc) {
    const __half2* pa = (const __half2*)&a;
    const __half2* pb = (const __half2*)&bu;
#pragma unroll
    for (int j = 0; j < 4; ++j) {
        float2 f = __half22float2(pa[j]);
        qc[2 * j] = f.x; qc[2 * j + 1] = f.y;
    }
#pragma unroll
    for (int j = 0; j < 4; ++j) {
        float2 f = __half22float2(pb[j]);
        qc[8 + 2 * j] = f.x; qc[8 + 2 * j + 1] = f.y;
    }
}

// pack 16 scaled channels into two uint4 (8 x half2)
__device__ __forceinline__ void pack_px(const float* u, float scale,
                                        uint4& a, uint4& bu) {
    __half2* pa = (__half2*)&a;
    __half2* pb = (__half2*)&bu;
    pa[0] = __floats2half2_rn(u[0]  * scale, u[1]  * scale);
    pa[1] = __floats2half2_rn(u[2]  * scale, u[3]  * scale);
    pa[2] = __floats2half2_rn(u[4]  * scale, u[5]  * scale);
    pa[3] = __floats2half2_rn(u[6]  * scale, u[7]  * scale);
    pb[0] = __floats2half2_rn(u[8]  * scale, u[9]  * scale);
    pb[1] = __floats2half2_rn(u[10] * scale, u[11] * scale);
    pb[2] = __floats2half2_rn(u[12] * scale, u[13] * scale);
    pb[3] = __floats2half2_rn(u[14] * scale, u[15] * scale);
}

__device__ __forceinline__ void st_raw(unsigned* q, int p, int cg,
                                       uint4 a, uint4 bu) {
    int ia = p * 32 + ((cg * 8) ^ ((p & 7) << 2));
    *(uint4*)&q[ia] = a;
    *(uint4*)&q[ia ^ 4] = bu;
}

__device__ __forceinline__ void st_px(unsigned* q, int p, int cg,
                                      const float* u, float scale) {
    uint4 a, bu;
    pack_px(u, scale, a, bu);
    st_raw(q, p, cg, a, bu);
}

// 4-way exclusive prefix + totals over channel-groups (shfl partners at
// pxl+16g share the same task id -> divergence-safe in partial rounds)
__device__ __forceinline__ void scan4(float Aloc, float Bloc, int pxl, int cg,
                                      float& Ar, float& Br, float& T, float& E) {
    float A0 = __shfl(Aloc, pxl),      A1 = __shfl(Aloc, pxl + 16),
          A2 = __shfl(Aloc, pxl + 32), A3 = __shfl(Aloc, pxl + 48);
    float B0 = __shfl(Bloc, pxl),      B1 = __shfl(Bloc, pxl + 16),
          B2 = __shfl(Bloc, pxl + 32), B3 = __shfl(Bloc, pxl + 48);
    T = A0 + A1 + A2 + A3;  E = B0 + B1 + B2 + B3;
    Ar = 0.f; Br = 0.f;
    if (cg > 0) { Ar += A0; Br += B0; }
    if (cg > 1) { Ar += A1; Br += B1; }
    if (cg > 2) { Ar += A2; Br += B2; }
}

// tv[i] = t[e] (pre-scaled by log2e via kaff); qc = q0 center (softmax of the
// ORIGINAL logits). q_new[d] = qc[d]*2^(-qhat2[d])/sum == softmax(lg - q_hat).
__device__ __forceinline__ float finish_mult(float* tv, const float* qc,
                                             int pxl, int cg) {
    float Aloc = 0.f, Bloc = 0.f;
#pragma unroll
    for (int i = 0; i < 16; ++i) {
        float e = (float)(cg * 16 + i);
        Aloc += tv[i]; Bloc += e * tv[i];
    }
    float Ar, Br, T, E;
    scan4(Aloc, Bloc, pxl, cg, Ar, Br, T, E);
    float s = 0.f;
#pragma unroll
    for (int i = 0; i < 16; ++i) {
        float e = (float)(cg * 16 + i);
        Ar += tv[i]; Br += e * tv[i];
        float qh2 = 2.f * (e * Ar - Br) + E - e * T;   // = q_hat * log2e
        tv[i] = qc[i] * fexp2(-qh2);
        s += tv[i];
    }
    s += __shfl_xor(s, 16);
    s += __shfl_xor(s, 32);
    return 1.f / s;
}

// px-major pre-masked dup-half2 kaff: uint4 + uint4 + uint from one record
__device__ __forceinline__ void load_kh(const unsigned* kfbp, int n,
                                        __half2* kh) {
    const unsigned* kp = kfbp + (size_t)n * 12;
    uint4 a = *(const uint4*)(kp + 0);
    uint4 bq = *(const uint4*)(kp + 4);
    unsigned c = kp[8];
    kh[0] = *(__half2*)&a.x; kh[1] = *(__half2*)&a.y;
    kh[2] = *(__half2*)&a.z; kh[3] = *(__half2*)&a.w;
    kh[4] = *(__half2*)&bq.x; kh[5] = *(__half2*)&bq.y;
    kh[6] = *(__half2*)&bq.z; kh[7] = *(__half2*)&bq.w;
    kh[8] = *(__half2*)&c;
}

// 9-tap stencil from an LDS q-region into tv[16] (f32), via packed f16 FMA
__device__ __forceinline__ void stencil9(const unsigned* qs, int rowstride,
                                         int py, int px, int cg,
                                         const __half2* kh, float* tv) {
    __half2 tv2[8];
#pragma unroll
    for (int j = 0; j < 8; ++j) tv2[j] = __float2half2_rn(0.f);
    int base = (py + 1) * rowstride + (px + 1);
#pragma unroll
    for (int tap = 0; tap < 9; ++tap) {
        int dy = tap / 3 - 1, dx = tap - (tap / 3) * 3 - 1;
        acc_tap(qs, base + dy * rowstride + dx, cg, kh[tap], tv2);
    }
#pragma unroll
    for (int j = 0; j < 8; ++j) {
        float2 f = __half22float2(tv2[j]);
        tv[2 * j] = f.x; tv[2 * j + 1] = f.y;
    }
}

// ---------------------------------------------------------------------------
// Fused CRF per 8x16 out-tile (task = 1 px, 4 lanes x 16 ch), 512 threads.
// Single aliased LDS buffer (30.7 KB): holds q0 during P0/P1, then q1.
//   P0: q0 = softmax(logits) on 12x20 -> LDS
//   P1: q1 = normalize(q0_center * 2^-qhat1), qhat1 from q0 stencil
//       + each thread stashes q0 center of its P2 pixel in regs      [barrier]
//       store q1 into the same LDS buffer                            [barrier]
//   P2: qhat2 from q1 stencil; q2 = normalize(q0c_regs * 2^-qhat2) -> global
// P1/P2 never read logits; exp is raw v_exp_f32 via kaff log2e pre-scale;
// kaff is pre-masked dup-half2, so tasks do zero masking/convert work.
// ---------------------------------------------------------------------------
__global__ __launch_bounds__(512) void fused_crf_kernel(
    const float* __restrict__ logits, const unsigned* __restrict__ kaffp,
    float* __restrict__ qout)
{
    __shared__ unsigned qs[NP0 * 32];   // 30,720 B (q0, later q1)

    const int t = threadIdx.x;
    const int lane = t & 63;
    const int wv = t >> 6;          // 0..7
    const int pxl = lane & 15;
    const int cg = lane >> 4;       // channels [16cg, 16cg+16)
    const int b = blockIdx.y;
    const int tid16 = wv * 16 + pxl;  // 0..127

    const int bid = blockIdx.x;     // XCD swizzle (1408 % 8 == 0 -> bijective)
    const int pb = (bid & 7) * (NTILES / 8) + (bid >> 3);
    const int tyr = pb / NTX, txc = pb - tyr * NTX;
    const int y0 = tyr * TY, x0 = txc * TX;

    const float* lgb = logits + ((size_t)b * DD + cg * 16) * HWN;
    const unsigned* kfbp = kaffp + (size_t)b * HWN * 12;

    // ---------------- P0: q0 = softmax(logits) on 12x20 ----------------
    for (int r = 0; r < 2; ++r) {
        int id = r * 128 + tid16;
        if (id < NP0) {
            int py = id / RX0, px = id - py * RX0;
            int gy = min(max(y0 - 2 + py, 0), HH - 1);
            int gx = min(max(x0 - 2 + px, 0), WW - 1);
            const float* lg = lgb + gy * WW + gx;
            float v[16];
            float s = 0.f;
#pragma unroll
            for (int i = 0; i < 16; ++i) {
                v[i] = __expf(lg[(size_t)i * HWN]);
                s += v[i];
            }
            s += __shfl_xor(s, 16);
            s += __shfl_xor(s, 32);
            st_px(qs, id, cg, v, 1.0f / s);
        }
    }
    __syncthreads();

    // ---------------- P1: q1 on 10x18, results in regs ----------------
    uint4 aA, buA;
    {   // round A: id = tid16 (0..127, always < NP1)
        int py = tid16 / RX1, px = tid16 - py * RX1;
        int gy = y0 - 1 + py, gx = x0 - 1 + px;
        int cy = min(max(gy, 0), HH - 1), cx = min(max(gx, 0), WW - 1);
        int n = cy * WW + cx;
        __half2 kh[9];
        load_kh(kfbp, n, kh);
        float tv[16];
        stencil9(qs, RX0, py, px, cg, kh, tv);
        uint4 ca, cb2;
        ld_raw(qs, (py + 1) * RX0 + (px + 1), cg, ca, cb2);
        float qc[16];
        unpack_px(ca, cb2, qc);
        float inv = finish_mult(tv, qc, pxl, cg);
        pack_px(tv, inv, aA, buA);
    }
    const int idB = 128 + tid16;
    const bool validB = idB < NP1;
    uint4 aB, buB;
    if (validB) {   // round B partial; shfl partners share id -> safe
        int py = idB / RX1, px = idB - py * RX1;
        int gy = y0 - 1 + py, gx = x0 - 1 + px;
        int cy = min(max(gy, 0), HH - 1), cx = min(max(gx, 0), WW - 1);
        int n = cy * WW + cx;
        __half2 kh[9];
        load_kh(kfbp, n, kh);
        float tv[16];
        stencil9(qs, RX0, py, px, cg, kh, tv);
        uint4 ca, cb2;
        ld_raw(qs, (py + 1) * RX0 + (px + 1), cg, ca, cb2);
        float qc[16];
        unpack_px(ca, cb2, qc);
        float inv = finish_mult(tv, qc, pxl, cg);
        pack_px(tv, inv, aB, buB);
    }

    // stash q0 center of this thread's P2 pixel (base for P2's softmax)
    uint4 q0cA, q0cB;
    {
        int pyc = tid16 >> 4, pxc = tid16 & 15;          // P2 pixel
        ld_raw(qs, (pyc + 2) * RX0 + (pxc + 2), cg, q0cA, q0cB);
    }
    __syncthreads();   // all q0 reads complete -> buffer reusable

    st_raw(qs, tid16, cg, aA, buA);
    if (validB) st_raw(qs, idB, cg, aB, buB);
    __syncthreads();   // q1 fully written

    // ---------------- P2: q2 -> global, 8x16 ----------------
    {
        int py = tid16 >> 4, px = tid16 & 15;
        int gy = y0 + py, gx = x0 + px;      // always in image
        int n = gy * WW + gx;

        __half2 kh[9];
        load_kh(kfbp, n, kh);

        float tv[16];
        stencil9(qs, RX1, py, px, cg, kh, tv);
        float qc[16];
        unpack_px(q0cA, q0cB, qc);           // base = q0 (original softmax)
        float inv = finish_mult(tv, qc, pxl, cg);

        float* qo = qout + ((size_t)b * DD + cg * 16) * HWN + n;
#pragma unroll
        for (int i = 0; i < 16; ++i) qo[(size_t)i * HWN] = tv[i] * inv;
    }
}

// ---------------------------------------------------------------------------
extern "C" void kernel_launch(void* const* d_in, const int* in_sizes, int n_in,
                              void* d_out, int out_size, void* d_ws, size_t ws_size,
                              hipStream_t stream) {
    const float* color  = (const float*)d_in[0];
    // d_in[1] = feats: unused by the forward pass
    const float* logits = (const float*)d_in[2];
    const float* wsp    = (const float*)d_in[3];

    float* q_out = (float*)d_out;
    unsigned* kaffp = (unsigned*)d_ws;    // [B,HW,12] dup-half2 px-major, 17.3 MB

    dim3 gridA(HWN / 256, BB);
    affinity_kernel<<<gridA, 256, 0, stream>>>(color, wsp, kaffp);

    dim3 gridF(NTILES, BB);               // 1408 tiles x 2 batches
    fused_crf_kernel<<<gridF, 512, 0, stream>>>(logits, kaffp, q_out);
}